// Round 15
// baseline (235.313 us; speedup 1.0000x reference)
//
#include <hip/hip_runtime.h>

#define IH 126
#define IW 126
#define HW 15876      // 126*126
#define OH 124
#define OW 124
#define OHW 15376     // 124*124

// Activations between kernels are HWC: a[(y*IW+x)*64 + c] (r6 win: 256 B runs).

// ---------------------------------------------------------------- conv_in (HWC out)
__global__ __launch_bounds__(256) void conv_in_kernel(
    const float* __restrict__ x, const float* __restrict__ w,
    const float* __restrict__ b, float* __restrict__ y)
{
  int tid = threadIdx.x;
  int oc = tid & 63;
  int w_ = __builtin_amdgcn_readfirstlane(tid >> 6);   // wave 0..3
  int pix = blockIdx.x * 4 + w_;
  if (pix >= HW) return;
  int h  = pix / IW;
  int wc = pix - h * IW;
  const float* wp = w + oc * 27;
  float acc = b[oc];
#pragma unroll
  for (int ci = 0; ci < 3; ci++)
#pragma unroll
    for (int ky = 0; ky < 3; ky++)
#pragma unroll
      for (int kx = 0; kx < 3; kx++)
        acc = fmaf(x[ci * 128 * 128 + (h + ky) * 128 + (wc + kx)],   // uniform
                   wp[ci * 9 + ky * 3 + kx], acc);
  y[pix * 64 + oc] = acc;
}

#define XSW(c, pos) ((c) ^ (((pos) & 7) << 3))
#define WVP4 36

// ---------------------------------------------------------------- involution v14
// r13 structure with phase B taken OFF the barrier chain:
//  - B reads its pixel's x[64] from GLOBAL HWC (256 B contiguous, L1-hot —
//    same lines phase A is fetching) + r0-proven uniform s_load weights.
//    No dependency on xs -> executes before any barrier, latency overlapped
//    with A's staging. wrs buffer dropped (-4 KB).
//  - Barriers 3 -> 2: one barrier covers xs + tss; C->D barrier unchanged.
//  - Edge tiles: clamped global address; affected t/w values feed only
//    store-guarded outputs. Phases C/D/store identical to r13.
// LDS 68,864 B -> 2 blocks/CU. All barriers unconditional (hang-audited r14).
__global__ __launch_bounds__(512, 4) void inv_kernel(
    const float* __restrict__ x, float* __restrict__ y,
    const float* __restrict__ wr, const float* __restrict__ br,
    const float* __restrict__ gam, const float* __restrict__ bet,
    const float* __restrict__ mu, const float* __restrict__ var,
    const float* __restrict__ wspan, const float* __restrict__ bspan)
{
  __shared__ __align__(16) float xs[140][68];    // 38,080 B
  __shared__ __align__(16) float wvs[196 * WVP4];// 28,224 B
  __shared__ __align__(16) float tss[640];       // 2,560 B; [32 px][20]

  int tid = threadIdx.x;
  int bx = blockIdx.x & 15, by = blockIdx.x >> 4;
  int ox0 = bx * 8, oy0 = by * 4;
  int xh0 = ox0 - 3, yh0 = oy0 - 3;

  int w_ = __builtin_amdgcn_readfirstlane(tid >> 6);  // wave 0..7
  int ln = tid & 63;
  int p  = ln & 31;                   // pixel 0..31 (upper 32 lanes duplicate)
  int prow = p >> 3, pcol = p & 7;

  // ---- Phase A: stage x halo (14 x 10 x 64 ch) from HWC into xs
  for (int idx = tid; idx < 140 * 16; idx += 512) {
    int pos = idx >> 4;
    int c4  = (idx & 15) << 2;
    int row = pos / 14;
    int col = pos - row * 14;
    int gy = yh0 + row, gx = xh0 + col;
    float4 v = make_float4(0.f, 0.f, 0.f, 0.f);
    if (gy >= 0 && gy < IH && gx >= 0 && gx < IW)
      v = *(const float4*)&x[(gy * IW + gx) * 64 + c4];
    *(float4*)&xs[pos][XSW(c4, pos)] = v;
  }

  // ---- Phase B (pre-barrier): t = ReLU(BN(Wr.x)) from GLOBAL x + s_load Wr
  {
    int gy = oy0 + prow; if (gy > IH - 1) gy = IH - 1;   // clamp: edge tiles
    int gx = ox0 + pcol; if (gx > IW - 1) gx = IW - 1;   // feed unstored rows
    const float* xg = &x[(gy * IW + gx) * 64];
    int cr0 = 2 * w_;
    const float* wa = wr + cr0 * 64;  // uniform -> s_load
    const float* wb = wa + 64;
    float a0 = 0.f, a1 = 0.f;
#pragma unroll
    for (int ci = 0; ci < 64; ci += 4) {
      float4 xv = *(const float4*)&xg[ci];
      a0 = fmaf(xv.x, wa[ci + 0], a0); a1 = fmaf(xv.x, wb[ci + 0], a1);
      a0 = fmaf(xv.y, wa[ci + 1], a0); a1 = fmaf(xv.y, wb[ci + 1], a1);
      a0 = fmaf(xv.z, wa[ci + 2], a0); a1 = fmaf(xv.z, wb[ci + 2], a1);
      a0 = fmaf(xv.w, wa[ci + 3], a0); a1 = fmaf(xv.w, wb[ci + 3], a1);
    }
    float s0 = gam[cr0]     * rsqrtf(var[cr0]     + 1e-5f);
    float s1 = gam[cr0 + 1] * rsqrtf(var[cr0 + 1] + 1e-5f);
    float t0 = (a0 + br[cr0]     - mu[cr0])     * s0 + bet[cr0];
    float t1 = (a1 + br[cr0 + 1] - mu[cr0 + 1]) * s1 + bet[cr0 + 1];
    if (ln < 32) {
      tss[p * 20 + cr0]     = fmaxf(t0, 0.f);
      tss[p * 20 + cr0 + 1] = fmaxf(t1, 0.f);
    }
  }
  __syncthreads();                     // xs writes + tss writes both visible

  // ---- Phase C: span. s_load weight batches; results in regs; writes deferred
  {
    float tv[16];
#pragma unroll
    for (int i = 0; i < 4; i++) {
      float4 t4 = *(const float4*)&tss[p * 20 + 4 * i];
      tv[4 * i] = t4.x; tv[4 * i + 1] = t4.y;
      tv[4 * i + 2] = t4.z; tv[4 * i + 3] = t4.w;
    }
    float wv[25];
#pragma unroll
    for (int j = 0; j < 25; j++) {
      int pair = w_ + 8 * j;           // wave-uniform
      float a = 0.f;
      if (pair < 196) {
        const float* wk = wspan + pair * 16;   // uniform -> s_load_dwordx16
        a = bspan[pair];
#pragma unroll
        for (int i = 0; i < 16; i++) a = fmaf(tv[i], wk[i], a);
      }
      wv[j] = a;
    }
    if (ln < 32) {
#pragma unroll
      for (int j = 0; j < 25; j++) {
        int pair = w_ + 8 * j;
        if (pair < 196) wvs[pair * WVP4 + pcol * 4 + prow] = wv[j];
      }
    }
  }
  __syncthreads();

  // ---- Phase D: einsum. wave = output column w_, lane = channel. (all-LDS)
  float acc0 = 0.f, acc1 = 0.f, acc2 = 0.f, acc3 = 0.f;
  {
    int c = ln;
    int g = ln >> 4;
    float xw[4][7];
#pragma unroll
    for (int r = 0; r < 4; r++)
#pragma unroll
      for (int kx = 0; kx < 7; kx++) {
        int pos = r * 14 + w_ + kx;
        xw[r][kx] = xs[pos][XSW(c, pos)];
      }
#pragma unroll
    for (int ky = 0; ky < 7; ky++) {
      if (ky > 0) {
#pragma unroll
        for (int r = 0; r < 3; r++)
#pragma unroll
          for (int kx = 0; kx < 7; kx++) xw[r][kx] = xw[r + 1][kx];
#pragma unroll
        for (int kx = 0; kx < 7; kx++) {
          int pos = (ky + 3) * 14 + w_ + kx;
          xw[3][kx] = xs[pos][XSW(c, pos)];
        }
      }
#pragma unroll
      for (int kx = 0; kx < 7; kx++) {
        int k = ky * 7 + kx;
        float4 w4 = *(const float4*)&wvs[(g * 49 + k) * WVP4 + w_ * 4];
        acc0 = fmaf(w4.x, xw[0][kx], acc0);
        acc1 = fmaf(w4.y, xw[1][kx], acc1);
        acc2 = fmaf(w4.z, xw[2][kx], acc2);
        acc3 = fmaf(w4.w, xw[3][kx], acc3);
      }
    }
  }

  // ---- direct HWC store (outer ReLU fused)
  {
    int c = ln;
    int gx = ox0 + w_;
    if (gx < IW) {
      int base = (oy0 * IW + gx) * 64 + c;
      y[base]               = fmaxf(acc0, 0.f);
      y[base + 1 * IW * 64] = fmaxf(acc1, 0.f);
      if (oy0 + 2 < IH) y[base + 2 * IW * 64] = fmaxf(acc2, 0.f);
      if (oy0 + 3 < IH) y[base + 3 * IW * 64] = fmaxf(acc3, 0.f);
    }
  }
}

// ---------------------------------------------------------------- conv_out prep
__global__ __launch_bounds__(256) void transpose_w_kernel(
    const float* __restrict__ w, float* __restrict__ wt)
{
  int i = blockIdx.x * 256 + threadIdx.x;
  if (i >= 128 * 64 * 9) return;
  int oc = i / 576;
  int rem = i - oc * 576;
  int ci = rem / 9;
  int k = rem - ci * 9;
  wt[(k * 64 + ci) * 128 + oc] = w[i];
}

// ---------------------------------------------------------------- conv_out v3 (FROZEN)
// Best measured (43 us). Five alternatives (v4-v8) all regressed; do not touch.
__global__ __launch_bounds__(256, 6) void conv_out_kernel(
    const float* __restrict__ x, const float* __restrict__ wt,
    const float* __restrict__ b, float* __restrict__ y)
{
  __shared__ __align__(16) float xsm[16 * 100 * 4];   // 25,600 B
  int tid = threadIdx.x;
  int bx = blockIdx.x & 15, by = blockIdx.x >> 4;
  int oy0 = by * 8, ox0 = bx * 8;

  for (int u = tid; u < 1600; u += 256) {
    int cq = u / 100;
    int pos = u - cq * 100;
    int row = pos / 10;
    int col = pos - row * 10;
    int gy = oy0 + row, gx = ox0 + col;
    float4 v = make_float4(0.f, 0.f, 0.f, 0.f);
    if (gy < IH && gx < IW)
      v = *(const float4*)&x[(gy * IW + gx) * 64 + cq * 4];
    *(float4*)&xsm[u * 4] = v;
  }
  __syncthreads();

  int ln = tid & 63;
  int px = ln & 7, py = ln >> 3;
  int wv_ = __builtin_amdgcn_readfirstlane(tid >> 6);   // wave 0..3
  int oc8 = blockIdx.y * 32 + wv_ * 8;

  float acc[8];
#pragma unroll
  for (int j = 0; j < 8; j++) acc[j] = b[oc8 + j];

#pragma unroll
  for (int ky = 0; ky < 3; ky++) {
#pragma unroll
    for (int kx = 0; kx < 3; kx++) {
      int k = ky * 3 + kx;
      int pidx = (py + ky) * 10 + px + kx;
      const float* wp = wt + k * 64 * 128 + oc8;   // uniform -> s_loads
#pragma unroll 4
      for (int cq = 0; cq < 16; cq++) {
        float4 xv = *(const float4*)&xsm[(cq * 100 + pidx) * 4];
        const float* wq = wp + cq * 4 * 128;
#pragma unroll
        for (int j = 0; j < 8; j++) {
          acc[j] = fmaf(xv.x, wq[0 * 128 + j], acc[j]);
          acc[j] = fmaf(xv.y, wq[1 * 128 + j], acc[j]);
          acc[j] = fmaf(xv.z, wq[2 * 128 + j], acc[j]);
          acc[j] = fmaf(xv.w, wq[3 * 128 + j], acc[j]);
        }
      }
    }
  }

  int oy = oy0 + py, ox = ox0 + px;
  if (oy < OH && ox < OW) {
#pragma unroll
    for (int j = 0; j < 8; j++)
      y[(oc8 + j) * OHW + oy * OW + ox] = acc[j];
  }
}

// ---------------------------------------------------------------- launch
extern "C" void kernel_launch(void* const* d_in, const int* in_sizes, int n_in,
                              void* d_out, int out_size, void* d_ws, size_t ws_size,
                              hipStream_t stream)
{
  const float* input = (const float*)d_in[0];
  const float* ciw   = (const float*)d_in[1];
  const float* cib   = (const float*)d_in[2];
  const float* wred  = (const float*)d_in[3];
  const float* bred  = (const float*)d_in[4];
  const float* gam   = (const float*)d_in[5];
  const float* bet   = (const float*)d_in[6];
  const float* mu    = (const float*)d_in[7];
  const float* var   = (const float*)d_in[8];
  const float* wspan = (const float*)d_in[9];
  const float* bspan = (const float*)d_in[10];
  const float* cow   = (const float*)d_in[11];
  const float* cob   = (const float*)d_in[12];
  float* out = (float*)d_out;

  float* bufA = (float*)d_ws;                 // HWC: 15876*64 = 1,016,064 floats
  float* bufB = bufA + (1 << 20);             // @ 4 MiB
  float* wt   = bufA + (1 << 21);             // @ 8 MiB, 73,728 floats

  transpose_w_kernel<<<288, 256, 0, stream>>>(cow, wt);
  conv_in_kernel<<<3969, 256, 0, stream>>>(input, ciw, cib, bufA);

  float* cur = bufA; float* nxt = bufB;
  for (int i = 0; i < 6; i++) {
    inv_kernel<<<512, 512, 0, stream>>>(cur, nxt,
        wred + i * 16 * 64, bred + i * 16, gam + i * 16, bet + i * 16,
        mu + i * 16, var + i * 16, wspan + i * 196 * 16, bspan + i * 196);
    float* t = cur; cur = nxt; nxt = t;
  }
  conv_out_kernel<<<dim3(256, 4), 256, 0, stream>>>(cur, wt, cob, out);
}